// Round 1
// baseline (300.125 us; speedup 1.0000x reference)
//
#include <hip/hip_runtime.h>
#include <math.h>

// Problem constants (match reference setup_inputs)
#define NH 8
#define DIM 128
#define KD 16
#define NB 16
#define NG 501
#define NPK 250
#define GK (NG * KD)            // 8016 floats per (h,b) projection slab
#define PSTRIDE (NH * NB * GK)  // 1,026,048 floats per projection index
// nf * log2(e) = 0.25 * 1.4426950408889634
#define QSCALE 0.36067376022224085f

// -------------------------------------------------------------------------
// Kernel 1: projections.  P7[p][h][b][g][k] = sum_d q[b,g,d]*W_p[h,d,k]
// p: 0=W_query 1=W_key 2=W_val 3=W1 4=W2 5=W3 6=W4.
// Q-type projections (p!=1,2) pre-scaled by QSCALE (nf*log2e) so the
// attention kernel can use exp2 directly; zmask zero-set is preserved.
// -------------------------------------------------------------------------
__device__ __forceinline__ void stage2048(float* dst, const float* src, int tid) {
  const float4* s4 = (const float4*)src;
  float4* d4 = (float4*)dst;
#pragma unroll
  for (int i = 0; i < 2; ++i) d4[tid + i * 256] = s4[tid + i * 256];
}

__global__ __launch_bounds__(256) void proj_kernel(
    const float* __restrict__ q,
    const float* __restrict__ w0, const float* __restrict__ w1,
    const float* __restrict__ w2, const float* __restrict__ w3,
    const float* __restrict__ w4, const float* __restrict__ w5,
    const float* __restrict__ w6,
    float* __restrict__ P7)
{
  __shared__ __align__(16) float qs[32 * 132];   // q tile, padded rows (16B aligned)
  __shared__ __align__(16) float ws[4 * 2048];   // up to 4 weight slabs [d][k]

  const int gt = blockIdx.x;         // 16 g-tiles of 32 rows
  const int b  = blockIdx.y;         // 16
  const int z  = blockIdx.z;         // 16 = h*2 + half
  const int h = z >> 1, half = z & 1;
  const int g0 = gt * 32;
  const int tid = threadIdx.x;

  // load q tile (float4, coalesced)
  for (int i = tid; i < 32 * 32; i += 256) {   // 1024 float4
    int r = i >> 5, c4 = (i & 31) * 4;
    int g = g0 + r;
    float4 v = make_float4(0.f, 0.f, 0.f, 0.f);
    if (g < NG) v = *(const float4*)&q[(size_t)(b * NG + g) * DIM + c4];
    *(float4*)&qs[r * 132 + c4] = v;
  }
  // load weight slabs for this half
  if (half == 0) {
    stage2048(ws + 0 * 2048, w0 + h * 2048, tid);
    stage2048(ws + 1 * 2048, w1 + h * 2048, tid);
    stage2048(ws + 2 * 2048, w2 + h * 2048, tid);
    stage2048(ws + 3 * 2048, w3 + h * 2048, tid);
  } else {
    stage2048(ws + 0 * 2048, w4 + h * 2048, tid);
    stage2048(ws + 1 * 2048, w5 + h * 2048, tid);
    stage2048(ws + 2 * 2048, w6 + h * 2048, tid);
  }
  __syncthreads();

  const int C = (half == 0) ? 64 : 48;   // columns = nproj*16
  const int rb = tid >> 5, cb = tid & 31;
  const int c0 = cb * 2;
  if (c0 < C) {
    const int r0 = rb * 4;
    const int p = c0 >> 4, k0 = c0 & 15;
    const float* wb = &ws[p * 2048 + k0];
    float acc[4][2] = {};
#pragma unroll 4
    for (int d = 0; d < DIM; ++d) {
      float2 wv = *(const float2*)&wb[d * 16];
#pragma unroll
      for (int i = 0; i < 4; ++i) {
        float qv = qs[(r0 + i) * 132 + d];
        acc[i][0] += qv * wv.x;
        acc[i][1] += qv * wv.y;
      }
    }
    const int pg = half * 4 + p;
    const float sc = (pg == 1 || pg == 2) ? 1.0f : QSCALE;
#pragma unroll
    for (int i = 0; i < 4; ++i) {
      int g = g0 + r0 + i;
      if (g < NG) {
        float* dst = &P7[(size_t)pg * PSTRIDE + ((size_t)(h * NB + b) * NG + g) * KD + k0];
        dst[0] = acc[i][0] * sc;
        dst[1] = acc[i][1] * sc;
      }
    }
  }
}

// -------------------------------------------------------------------------
// Kernel 2: fused attention.  One block = (row-half, b, h); rows in lanes,
// keys scalar-looped with online softmax in 16-key chunks.
// -------------------------------------------------------------------------
__device__ __forceinline__ float dot16(const float qv[16], const float* kp) {
  const float4* k4 = (const float4*)kp;
  float4 a = k4[0], b = k4[1], c = k4[2], d = k4[3];
  float s = qv[0] * a.x + qv[1] * a.y + qv[2] * a.z + qv[3] * a.w;
  s += qv[4] * b.x + qv[5] * b.y + qv[6] * b.z + qv[7] * b.w;
  s += qv[8] * c.x + qv[9] * c.y + qv[10] * c.z + qv[11] * c.w;
  s += qv[12] * d.x + qv[13] * d.y + qv[14] * d.z + qv[15] * d.w;
  return s;
}

__device__ __forceinline__ void load16(float* dst, const float* src) {
  if (src) {
    const float4* s4 = (const float4*)src;
#pragma unroll
    for (int i = 0; i < 4; ++i) {
      float4 t = s4[i];
      dst[4 * i + 0] = t.x; dst[4 * i + 1] = t.y;
      dst[4 * i + 2] = t.z; dst[4 * i + 3] = t.w;
    }
  } else {
#pragma unroll
    for (int i = 0; i < 16; ++i) dst[i] = 0.0f;
  }
}

template <bool ZM>
__device__ __forceinline__ void attn_pass(const float qv[16],
                                          const float* __restrict__ Ks,
                                          const float* __restrict__ Vs,
                                          int lo, int hi,
                                          float& m, float& l, float* O)
{
#pragma unroll 1
  for (int c0 = lo; c0 < hi; c0 += 16) {
    int n = hi - c0; if (n > 16) n = 16;
    float s[16];
#pragma unroll
    for (int j = 0; j < 16; ++j) {
      if (j < n) {
        float v = dot16(qv, &Ks[(c0 + j) * KD]);
        if (ZM) v = (v == 0.0f) ? -INFINITY : v;   // reference zmask
        s[j] = v;
      } else {
        s[j] = -INFINITY;
      }
    }
    float cm = s[0];
#pragma unroll
    for (int j = 1; j < 16; ++j) cm = fmaxf(cm, s[j]);
    float mn = fmaxf(m, cm);           // finite after first comp chunk
    float scale = exp2f(m - mn);       // m=-inf -> 0 on first chunk (O,l are 0)
    m = mn;
    l *= scale;
#pragma unroll
    for (int v = 0; v < 16; ++v) O[v] *= scale;
#pragma unroll
    for (int j = 0; j < 16; ++j) {
      if (j < n) {
        float p = exp2f(s[j] - mn);    // -inf -> 0
        l += p;
        const float4* v4 = (const float4*)&Vs[(c0 + j) * KD];
        float4 va = v4[0], vb = v4[1], vc = v4[2], vd = v4[3];
        O[0]  += p * va.x; O[1]  += p * va.y; O[2]  += p * va.z; O[3]  += p * va.w;
        O[4]  += p * vb.x; O[5]  += p * vb.y; O[6]  += p * vb.z; O[7]  += p * vb.w;
        O[8]  += p * vc.x; O[9]  += p * vc.y; O[10] += p * vc.z; O[11] += p * vc.w;
        O[12] += p * vd.x; O[13] += p * vd.y; O[14] += p * vd.z; O[15] += p * vd.w;
      }
    }
  }
}

__global__ __launch_bounds__(256) void attn_kernel(
    const float* __restrict__ P7, float* __restrict__ Hd)
{
  __shared__ __align__(16) float Ks[GK];
  __shared__ __align__(16) float Vs[GK];

  const int halfb = blockIdx.x;      // 2 row-halves
  const int b = blockIdx.y;          // 16
  const int h = blockIdx.z;          // 8
  const int tid = threadIdx.x;
  const size_t hb = (size_t)h * NB + b;

  const float* Kg = P7 + 1 * (size_t)PSTRIDE + hb * GK;
  const float* Vg = P7 + 2 * (size_t)PSTRIDE + hb * GK;
  for (int i = tid; i < GK / 4; i += 256) {
    ((float4*)Ks)[i] = ((const float4*)Kg)[i];
    ((float4*)Vs)[i] = ((const float4*)Vg)[i];
  }
  __syncthreads();

  const int r = halfb * 256 + tid;
  const bool valid = r < NG;
  const bool isPick = valid && r >= 1 && r <= NPK;
  const bool isDel  = valid && r > NPK;

  const float* Qb  = valid ? P7 + 0 * (size_t)PSTRIDE + hb * GK + (size_t)r * KD : nullptr;
  const float* QPb = isPick ? P7 + 3 * (size_t)PSTRIDE + hb * GK + (size_t)r * KD
                   : (isDel ? P7 + 5 * (size_t)PSTRIDE + hb * GK + (size_t)r * KD : nullptr);
  const float* QDb = isPick ? P7 + 4 * (size_t)PSTRIDE + hb * GK + (size_t)r * KD
                   : (isDel ? P7 + 6 * (size_t)PSTRIDE + hb * GK + (size_t)r * KD : nullptr);

  float qv[16], qp[16], qd[16];
  load16(qv, Qb);    // invalid rows: zero query -> harmless finite scores
  load16(qp, QPb);   // zero query + zmask -> all -inf == reference filler
  load16(qd, QDb);

  float m = -INFINITY, l = 0.0f, O[16];
#pragma unroll
  for (int v = 0; v < 16; ++v) O[v] = 0.0f;

  attn_pass<false>(qv, Ks, Vs, 0, NG, m, l, O);            // comp: all 501 keys
  attn_pass<true >(qp, Ks, Vs, 1, 1 + NPK, m, l, O);       // pick keys 1..250
  attn_pass<true >(qd, Ks, Vs, 1 + NPK, NG, m, l, O);      // delivery keys 251..500

  if (valid) {
    float inv = 1.0f / l;
    float* dst = Hd + (hb * NG + (size_t)r) * KD;
#pragma unroll
    for (int v = 0; v < 16; ++v) dst[v] = O[v] * inv;
  }
}

// -------------------------------------------------------------------------
// Kernel 3: output projection.  out[b,g,e] = sum_{h,k} Hd[h,b,g,k]*Wout[h,k,e]
// -------------------------------------------------------------------------
__global__ __launch_bounds__(256) void out_kernel(
    const float* __restrict__ Hd, const float* __restrict__ Wout,
    float* __restrict__ out)
{
  __shared__ __align__(16) float hs[32 * 132];   // 32 rows x 128 (h*16+k), padded
  __shared__ __align__(16) float wo[128 * 64];   // half of W_out columns

  const int R0 = blockIdx.x * 32;
  const int tid = threadIdx.x;
  const int NROWS = NB * NG;   // 8016

  for (int i = tid; i < 32 * 32; i += 256) {     // 1024 float4
    int rr = i >> 5, t = i & 31;
    int hh = t >> 2, k4 = (t & 3) * 4;
    int row = R0 + rr;
    float4 v = make_float4(0.f, 0.f, 0.f, 0.f);
    if (row < NROWS) {
      int bb = row / NG, g = row % NG;
      v = *(const float4*)&Hd[((size_t)(hh * NB + bb) * NG + g) * KD + k4];
    }
    *(float4*)&hs[rr * 132 + hh * 16 + k4] = v;
  }

  const int rb = tid >> 5, cb = tid & 31;
  const int r0 = rb * 4, e0 = cb * 2;

  for (int ep = 0; ep < 2; ++ep) {
    __syncthreads();   // iter0: hs ready; iter1: previous wo fully consumed
    for (int i = tid; i < 128 * 16; i += 256) {  // 2048 float4
      int dd = i >> 4, e4 = (i & 15) * 4;
      *(float4*)&wo[dd * 64 + e4] = *(const float4*)&Wout[dd * DIM + ep * 64 + e4];
    }
    __syncthreads();

    float acc[4][2] = {};
#pragma unroll 4
    for (int dd = 0; dd < 128; ++dd) {
      float2 wv = *(const float2*)&wo[dd * 64 + e0];
#pragma unroll
      for (int i = 0; i < 4; ++i) {
        float hv = hs[(r0 + i) * 132 + dd];
        acc[i][0] += hv * wv.x;
        acc[i][1] += hv * wv.y;
      }
    }
#pragma unroll
    for (int i = 0; i < 4; ++i) {
      int row = R0 + r0 + i;
      if (row < NROWS) {
        out[(size_t)row * DIM + ep * 64 + e0]     = acc[i][0];
        out[(size_t)row * DIM + ep * 64 + e0 + 1] = acc[i][1];
      }
    }
  }
}

// -------------------------------------------------------------------------
extern "C" void kernel_launch(void* const* d_in, const int* in_sizes, int n_in,
                              void* d_out, int out_size, void* d_ws, size_t ws_size,
                              hipStream_t stream)
{
  const float* q  = (const float*)d_in[0];
  const float* Wq = (const float*)d_in[1];
  const float* Wk = (const float*)d_in[2];
  const float* Wv = (const float*)d_in[3];
  const float* W1 = (const float*)d_in[4];
  const float* W2 = (const float*)d_in[5];
  const float* W3 = (const float*)d_in[6];
  const float* W4 = (const float*)d_in[7];
  const float* Wo = (const float*)d_in[8];
  float* out = (float*)d_out;

  float* P7 = (float*)d_ws;                       // 7 projections
  float* Hd = P7 + (size_t)7 * PSTRIDE;           // heads [h][b][g][k]

  proj_kernel<<<dim3(16, NB, 16), 256, 0, stream>>>(q, Wq, Wk, Wv, W1, W2, W3, W4, P7);
  attn_kernel<<<dim3(2, NB, NH), 256, 0, stream>>>(P7, Hd);
  out_kernel<<<dim3((NB * NG + 31) / 32), 256, 0, stream>>>(Hd, Wo, out);
}

// Round 3
// 176.968 us; speedup vs baseline: 1.6959x; 1.6959x over previous
//
#include <hip/hip_runtime.h>
#include <math.h>

// Problem constants (match reference setup_inputs)
#define NH 8
#define DIM 128
#define KD 16
#define NB 16
#define NG 501
#define NPK 250
#define QROWS 512                 // padded row count for projection arrays
// nf * log2(e) = 0.25 * 1.4426950408889634
#define QSCALE 0.36067376022224085f

typedef unsigned short ushort_t;
typedef __attribute__((ext_vector_type(8))) short short8v;   // 8 bf16 (4 VGPRs) MFMA frag
typedef __attribute__((ext_vector_type(4))) short short4v;
typedef __attribute__((ext_vector_type(2))) short short2v;
typedef __attribute__((ext_vector_type(4))) float f32x4;

#define MFMA(a, b, c) __builtin_amdgcn_mfma_f32_16x16x32_bf16(a, b, c, 0, 0, 0)

static __device__ __forceinline__ ushort_t f2bf(float x) {  // RNE, finite inputs only
  union { float f; unsigned u; } v; v.f = x;
  unsigned r = v.u + 0x7FFFu + ((v.u >> 16) & 1u);
  return (ushort_t)(r >> 16);
}
static __device__ __forceinline__ float bf2f(ushort_t h) {
  union { unsigned u; float f; } v; v.u = ((unsigned)h) << 16;
  return v.f;
}

// -------------------------------------------------------------------------
// Kernel 1: projections -> bf16 hi/lo split.
//  half0: Qc hi/lo (scaled), K hi/lo ([key][32] = [hi16|lo16]), V^T (bf16)
//  half1: QP hi/lo (W1 for pick rows / W3 for del rows), QD hi/lo (W2/W4).
//  QP/QD row g=0 zeroed (zmask filler). Pad rows (>=NG) get zeros via qs.
// -------------------------------------------------------------------------
__device__ __forceinline__ void stage2048(float* dst, const float* src, int tid) {
  const float4* s4 = (const float4*)src;
  float4* d4 = (float4*)dst;
#pragma unroll
  for (int i = 0; i < 2; ++i) d4[tid + i * 256] = s4[tid + i * 256];
}

__global__ __launch_bounds__(256) void proj_kernel(
    const float* __restrict__ q,
    const float* __restrict__ wq, const float* __restrict__ wk,
    const float* __restrict__ wv, const float* __restrict__ w1,
    const float* __restrict__ w2, const float* __restrict__ w3,
    const float* __restrict__ w4,
    ushort_t* __restrict__ QcH, ushort_t* __restrict__ QcL,
    ushort_t* __restrict__ QPH, ushort_t* __restrict__ QPL,
    ushort_t* __restrict__ QDH, ushort_t* __restrict__ QDL,
    ushort_t* __restrict__ Kb,  ushort_t* __restrict__ Vt)
{
  __shared__ __align__(16) float qs[32 * 132];
  __shared__ __align__(16) float ws[4 * 2048];

  const int gt = blockIdx.x, b = blockIdx.y, z = blockIdx.z;
  const int h = z >> 1, half = z & 1;
  const int g0 = gt * 32;
  const int tid = threadIdx.x;

  for (int i = tid; i < 32 * 32; i += 256) {   // q tile (zero-padded past NG)
    int r = i >> 5, c4 = (i & 31) * 4;
    int g = g0 + r;
    float4 v = make_float4(0.f, 0.f, 0.f, 0.f);
    if (g < NG) v = *(const float4*)&q[(size_t)(b * NG + g) * DIM + c4];
    *(float4*)&qs[r * 132 + c4] = v;
  }
  if (half == 0) {
    stage2048(ws + 0 * 2048, wq + h * 2048, tid);
    stage2048(ws + 1 * 2048, wk + h * 2048, tid);
    stage2048(ws + 2 * 2048, wv + h * 2048, tid);
  } else {
    stage2048(ws + 0 * 2048, w1 + h * 2048, tid);
    stage2048(ws + 1 * 2048, w2 + h * 2048, tid);
    stage2048(ws + 2 * 2048, w3 + h * 2048, tid);
    stage2048(ws + 3 * 2048, w4 + h * 2048, tid);
  }
  __syncthreads();

  const int rb = tid >> 5, cb = tid & 31;
  const int r0 = rb * 4;
  const size_t hb = (size_t)h * NB + b;
  const int c0 = cb * 2;

  if (half == 0) {
    if (c0 < 48) {
      const int p = c0 >> 4, k0 = c0 & 15;
      const float* wbp = &ws[p * 2048 + k0];
      float acc[4][2] = {};
#pragma unroll 4
      for (int d = 0; d < DIM; ++d) {
        float2 wv2 = *(const float2*)&wbp[d * 16];
#pragma unroll
        for (int i = 0; i < 4; ++i) {
          float qv = qs[(r0 + i) * 132 + d];
          acc[i][0] += qv * wv2.x;
          acc[i][1] += qv * wv2.y;
        }
      }
      if (p == 2) {      // V^T[v][g]: pack 4 consecutive g per kd col (bf16)
#pragma unroll
        for (int c = 0; c < 2; ++c) {
          short4v pk;
          pk[0] = (short)f2bf(acc[0][c]); pk[1] = (short)f2bf(acc[1][c]);
          pk[2] = (short)f2bf(acc[2][c]); pk[3] = (short)f2bf(acc[3][c]);
          *(short4v*)&Vt[hb * (16 * QROWS) + (size_t)(k0 + c) * QROWS + (g0 + r0)] = pk;
        }
      } else {
        const float sc = (p == 0) ? QSCALE : 1.0f;
#pragma unroll
        for (int i = 0; i < 4; ++i) {
          int g = g0 + r0 + i;
          float x0 = acc[i][0] * sc, x1 = acc[i][1] * sc;
          ushort_t h0 = f2bf(x0), h1 = f2bf(x1);
          ushort_t lo0 = f2bf(x0 - bf2f(h0)), lo1 = f2bf(x1 - bf2f(h1));
          short2v ph; ph[0] = (short)h0;  ph[1] = (short)h1;
          short2v pl; pl[0] = (short)lo0; pl[1] = (short)lo1;
          if (p == 0) {
            size_t off = hb * (size_t)(QROWS * 16) + (size_t)g * 16 + k0;
            *(short2v*)&QcH[off] = ph;
            *(short2v*)&QcL[off] = pl;
          } else {
            size_t off = hb * (size_t)(QROWS * 32) + (size_t)g * 32 + k0;
            *(short2v*)&Kb[off] = ph;        // hi in k 0..15
            *(short2v*)&Kb[off + 16] = pl;   // lo in k 16..31
          }
        }
      }
    }
  } else {
    if (c0 < 32) {
      const int p = c0 >> 4, k0 = c0 & 15;   // p: 0->QP(W1/W3), 1->QD(W2/W4)
      const float* sA = &ws[(p == 0 ? 0 : 1) * 2048 + k0];
      const float* sB = &ws[(p == 0 ? 2 : 3) * 2048 + k0];
      const bool mixed = (g0 == 224);         // only tile straddling 250/251
      const bool useB  = (g0 >= 251);
      const float* s1 = useB ? sB : sA;
      float accA[4][2] = {}, accB[4][2] = {};
#pragma unroll 4
      for (int d = 0; d < DIM; ++d) {
        float2 wv2 = *(const float2*)&s1[d * 16];
#pragma unroll
        for (int i = 0; i < 4; ++i) {
          float qv = qs[(r0 + i) * 132 + d];
          accA[i][0] += qv * wv2.x;
          accA[i][1] += qv * wv2.y;
        }
      }
      if (mixed) {
#pragma unroll 4
        for (int d = 0; d < DIM; ++d) {
          float2 wv2 = *(const float2*)&sB[d * 16];
#pragma unroll
        for (int i = 0; i < 4; ++i) {
            float qv = qs[(r0 + i) * 132 + d];
            accB[i][0] += qv * wv2.x;
            accB[i][1] += qv * wv2.y;
          }
        }
      }
      ushort_t* dstH = (p == 0) ? QPH : QDH;
      ushort_t* dstL = (p == 0) ? QPL : QDL;
#pragma unroll
      for (int i = 0; i < 4; ++i) {
        int g = g0 + r0 + i;
        float a0, a1;
        if (mixed && g > NPK) { a0 = accB[i][0]; a1 = accB[i][1]; }
        else                  { a0 = accA[i][0]; a1 = accA[i][1]; }
        if (g == 0) { a0 = 0.f; a1 = 0.f; }    // zmask filler row
        float x0 = a0 * QSCALE, x1 = a1 * QSCALE;
        ushort_t h0 = f2bf(x0), h1 = f2bf(x1);
        ushort_t lo0 = f2bf(x0 - bf2f(h0)), lo1 = f2bf(x1 - bf2f(h1));
        short2v ph; ph[0] = (short)h0;  ph[1] = (short)h1;
        short2v pl; pl[0] = (short)lo0; pl[1] = (short)lo1;
        size_t off = hb * (size_t)(QROWS * 16) + (size_t)g * 16 + k0;
        *(short2v*)&dstH[off] = ph;
        *(short2v*)&dstL[off] = pl;
      }
    }
  }
}

// -------------------------------------------------------------------------
// Kernel 2: fused MFMA attention, split-precision scores.
//  Block = (rowtile of 128, b, h); 4 waves x 32 q-rows. Swapped S-mfma:
//  D[key][qrow] = K x Q^T with A=[Kh|Kl] (32 k-slots), 2 MFMAs per score.
//  Blocked LDS layouts: bank-uniform b128 reads, no padding waste.
// -------------------------------------------------------------------------
__global__ __launch_bounds__(256, 2) void attn_kernel(
    const ushort_t* __restrict__ QcH, const ushort_t* __restrict__ QcL,
    const ushort_t* __restrict__ QPH, const ushort_t* __restrict__ QPL,
    const ushort_t* __restrict__ QDH, const ushort_t* __restrict__ QDL,
    const ushort_t* __restrict__ Kb,  const ushort_t* __restrict__ Vt,
    float* __restrict__ Hd)
{
  __shared__ __align__(16) ushort_t Klds[16384];      // [ch32][lcol16][lh4][8] == linear copy of Kb slab
  __shared__ __align__(16) ushort_t Vlds[8192];       // [grp16][lh4][v16][8]
  __shared__ __align__(16) ushort_t Plds[4][32][40];  // per-wave P: qrow x key (80B rows)

  const int rt = blockIdx.x, b = blockIdx.y, h = blockIdx.z;
  const int tid = threadIdx.x;
  const int wid = tid >> 6, lane = tid & 63;
  const int lhalf = lane >> 4, lcol = lane & 15;
  const size_t hb = (size_t)h * NB + b;

  // stage K: blocked dest order == linear source order -> straight 16B copy
  const ushort_t* Kg = Kb + hb * (size_t)(QROWS * 32);
  for (int c = tid; c < 2048; c += 256)
    *(short8v*)&Klds[c * 8] = *(const short8v*)(Kg + (size_t)c * 8);

  // stage V^T -> blocked [grp][lh][v][8]
  const ushort_t* Vg = Vt + hb * (size_t)(16 * QROWS);
#pragma unroll
  for (int it = 0; it < 4; ++it) {
    int c = it * 256 + tid;
    int blk = (it * 16) + (c & 15);      // key-octet 0..63 (blkh = it)
    int v = (c >> 4) & 15;
    int grp = blk >> 2, lh = blk & 3;
    short8v val = *(const short8v*)(Vg + (size_t)v * QROWS + blk * 8);
    *(short8v*)&Vlds[((grp * 4 + lh) * 16 + v) * 8] = val;
  }
  __syncthreads();

  // Q fragments in regs for the whole key loop.
  //  B1 (hi) : all lanes, k-slot (lhalf&1)*8 -> [Qh|Qh]
  //  B2 (lo) : lanes lhalf<2 hold Ql, else 0 -> [Ql|0]
  const int wrow = rt * 128 + wid * 32;
  short8v qch[2], qcl[2], qph[2], qpl[2], qdh[2], qdl[2];
#pragma unroll
  for (int f = 0; f < 2; ++f) {
    int row = wrow + f * 16 + lcol;              // < 512, pad rows are zeros
    size_t off = hb * (size_t)(QROWS * 16) + (size_t)row * 16;
    size_t offh = off + (lhalf & 1) * 8;
    qch[f] = *(const short8v*)(QcH + offh);
    qph[f] = *(const short8v*)(QPH + offh);
    qdh[f] = *(const short8v*)(QDH + offh);
    short8v zl = {0,0,0,0,0,0,0,0};
    qcl[f] = zl; qpl[f] = zl; qdl[f] = zl;
    if (lhalf < 2) {
      size_t offl = off + lhalf * 8;
      qcl[f] = *(const short8v*)(QcL + offl);
      qpl[f] = *(const short8v*)(QPL + offl);
      qdl[f] = *(const short8v*)(QDL + offl);
    }
  }

  const f32x4 zero4 = {0.f, 0.f, 0.f, 0.f};
  f32x4 Oacc[2] = {zero4, zero4};
  float lsum[2] = {0.f, 0.f};
  ushort_t* Pw = &Plds[wid][0][0];

#pragma unroll 1
  for (int grp = 0; grp < 16; ++grp) {
#pragma unroll
    for (int half = 0; half < 2; ++half) {
      const int ch = grp * 2 + half;
      const int kbase = ch * 16;
      // A-frag: keys kbase+lcol, k-slots [Kh(0..15)|Kl(16..31)]
      short8v ka = *(const short8v*)&Klds[((ch * 16 + lcol) * 4 + lhalf) * 8];
#pragma unroll
      for (int qf = 0; qf < 2; ++qf) {
        f32x4 sc = MFMA(ka, qcl[qf], zero4);   // Kh*Ql
        sc = MFMA(ka, qch[qf], sc);            // + Kh*Qh + Kl*Qh
        f32x4 se;
        if (ch == 15) {                        // straddles pick/del at key 250/251
          f32x4 sp = MFMA(ka, qpl[qf], zero4); sp = MFMA(ka, qph[qf], sp);
          f32x4 sd = MFMA(ka, qdl[qf], zero4); sd = MFMA(ka, qdh[qf], sd);
#pragma unroll
          for (int rg = 0; rg < 4; ++rg) {
            int key = kbase + lhalf * 4 + rg;
            se[rg] = (key <= NPK) ? sp[rg] : sd[rg];
          }
        } else if (ch <= 14) {                 // pure pick-key range
          se = MFMA(ka, qpl[qf], zero4); se = MFMA(ka, qph[qf], se);
        } else {                               // pure delivery-key range
          se = MFMA(ka, qdl[qf], zero4); se = MFMA(ka, qdh[qf], se);
        }
        float pv[4];
#pragma unroll
        for (int rg = 0; rg < 4; ++rg) {
          int key = kbase + lhalf * 4 + rg;
          float ec = __builtin_amdgcn_exp2f(sc[rg]);
          float ee = (se[rg] == 0.0f) ? 0.0f : __builtin_amdgcn_exp2f(se[rg]); // zmask
          float pt = ec + ((key >= 1) ? ee : 0.0f);   // key 0: comp only
          pt = (key < NG) ? pt : 0.0f;                // pad keys contribute 0
          pv[rg] = pt;
        }
        short4v pk;
        pk[0] = (short)f2bf(pv[0]); pk[1] = (short)f2bf(pv[1]);
        pk[2] = (short)f2bf(pv[2]); pk[3] = (short)f2bf(pv[3]);
        // accumulate the ROUNDED p so numerator/denominator are consistent
        lsum[qf] += bf2f((ushort_t)pk[0]) + bf2f((ushort_t)pk[1]) +
                    bf2f((ushort_t)pk[2]) + bf2f((ushort_t)pk[3]);
        *(short4v*)&Pw[(qf * 16 + lcol) * 40 + half * 16 + lhalf * 4] = pk;
      }
    }
    // same-wave LDS write->read ordering (P is wave-private; no barrier needed)
    asm volatile("s_waitcnt lgkmcnt(0)" ::: "memory");
    __builtin_amdgcn_sched_barrier(0);
#pragma unroll
    for (int qf = 0; qf < 2; ++qf) {
      short8v pa = *(const short8v*)&Pw[(qf * 16 + lcol) * 40 + lhalf * 8];
      short8v vb = *(const short8v*)&Vlds[((grp * 4 + lhalf) * 16 + lcol) * 8];
      Oacc[qf] = MFMA(pa, vb, Oacc[qf]);
    }
  }

  // normalize + store: O C-frag row = lhalf*4+rg (qrow), col v = lcol
#pragma unroll
  for (int qf = 0; qf < 2; ++qf) {
    float l = lsum[qf];            // lane's partial for qrow = lcol
    l += __shfl_xor(l, 16);
    l += __shfl_xor(l, 32);
    float inv = 1.0f / l;
#pragma unroll
    for (int rg = 0; rg < 4; ++rg) {
      float invr = __shfl(inv, lhalf * 4 + rg);   // inv for qrow lhalf*4+rg
      float o = Oacc[qf][rg] * invr;
      int row = wrow + qf * 16 + lhalf * 4 + rg;
      if (row < NG) Hd[(hb * NG + (size_t)row) * KD + lcol] = o;
    }
  }
}

// -------------------------------------------------------------------------
// Kernel 3: output projection (unchanged, fp32).
// -------------------------------------------------------------------------
__global__ __launch_bounds__(256) void out_kernel(
    const float* __restrict__ Hd, const float* __restrict__ Wout,
    float* __restrict__ out)
{
  __shared__ __align__(16) float hs[32 * 132];
  __shared__ __align__(16) float wo[128 * 64];

  const int R0 = blockIdx.x * 32;
  const int tid = threadIdx.x;
  const int NROWS = NB * NG;

  for (int i = tid; i < 32 * 32; i += 256) {
    int rr = i >> 5, t = i & 31;
    int hh = t >> 2, k4 = (t & 3) * 4;
    int row = R0 + rr;
    float4 v = make_float4(0.f, 0.f, 0.f, 0.f);
    if (row < NROWS) {
      int bb = row / NG, g = row % NG;
      v = *(const float4*)&Hd[((size_t)(hh * NB + bb) * NG + g) * KD + k4];
    }
    *(float4*)&hs[rr * 132 + hh * 16 + k4] = v;
  }

  const int rb = tid >> 5, cb = tid & 31;
  const int r0 = rb * 4, e0 = cb * 2;

  for (int ep = 0; ep < 2; ++ep) {
    __syncthreads();
    for (int i = tid; i < 128 * 16; i += 256) {
      int dd = i >> 4, e4 = (i & 15) * 4;
      *(float4*)&wo[dd * 64 + e4] = *(const float4*)&Wout[dd * DIM + ep * 64 + e4];
    }
    __syncthreads();

    float acc[4][2] = {};
#pragma unroll 4
    for (int dd = 0; dd < 128; ++dd) {
      float2 wv = *(const float2*)&wo[dd * 64 + e0];
#pragma unroll
      for (int i = 0; i < 4; ++i) {
        float hv = hs[(r0 + i) * 132 + dd];
        acc[i][0] += hv * wv.x;
        acc[i][1] += hv * wv.y;
      }
    }
#pragma unroll
    for (int i = 0; i < 4; ++i) {
      int row = R0 + r0 + i;
      if (row < NROWS) {
        out[(size_t)row * DIM + ep * 64 + e0]     = acc[i][0];
        out[(size_t)row * DIM + ep * 64 + e0 + 1] = acc[i][1];
      }
    }
  }
}

// -------------------------------------------------------------------------
extern "C" void kernel_launch(void* const* d_in, const int* in_sizes, int n_in,
                              void* d_out, int out_size, void* d_ws, size_t ws_size,
                              hipStream_t stream)
{
  const float* q  = (const float*)d_in[0];
  const float* Wq = (const float*)d_in[1];
  const float* Wk = (const float*)d_in[2];
  const float* Wv = (const float*)d_in[3];
  const float* W1 = (const float*)d_in[4];
  const float* W2 = (const float*)d_in[5];
  const float* W3 = (const float*)d_in[6];
  const float* W4 = (const float*)d_in[7];
  const float* Wo = (const float*)d_in[8];
  float* out = (float*)d_out;

  char* wsb = (char*)d_ws;
  ushort_t* QcH = (ushort_t*)(wsb + (0u  << 20));   // 2 MB each (128 hb x 512 x 16 bf16)
  ushort_t* QcL = (ushort_t*)(wsb + (2u  << 20));
  ushort_t* QPH = (ushort_t*)(wsb + (4u  << 20));
  ushort_t* QPL = (ushort_t*)(wsb + (6u  << 20));
  ushort_t* QDH = (ushort_t*)(wsb + (8u  << 20));
  ushort_t* QDL = (ushort_t*)(wsb + (10u << 20));
  ushort_t* Kb  = (ushort_t*)(wsb + (12u << 20));   // 4 MB (512 x 32 per hb)
  ushort_t* Vt  = (ushort_t*)(wsb + (16u << 20));   // 2 MB
  float*    Hd  = (float*)   (wsb + (18u << 20));   // 4.1 MB

  proj_kernel<<<dim3(16, NB, 16), 256, 0, stream>>>(q, Wq, Wk, Wv, W1, W2, W3, W4,
                                                    QcH, QcL, QPH, QPL, QDH, QDL, Kb, Vt);
  attn_kernel<<<dim3(4, NB, NH), 256, 0, stream>>>(QcH, QcL, QPH, QPL, QDH, QDL, Kb, Vt, Hd);
  out_kernel<<<dim3((NB * NG + 31) / 32), 256, 0, stream>>>(Hd, Wo, out);
}

// Round 4
// 133.486 us; speedup vs baseline: 2.2484x; 1.3257x over previous
//
#include <hip/hip_runtime.h>
#include <math.h>

// Problem constants (match reference setup_inputs)
#define NH 8
#define DIM 128
#define KD 16
#define NB 16
#define NG 501
#define NPK 250
#define QROWS 512                 // padded row count for projection arrays
// nf * log2(e) = 0.25 * 1.4426950408889634
#define QSCALE 0.36067376022224085f

typedef unsigned short ushort_t;
typedef __attribute__((ext_vector_type(8))) short short8v;   // 8 bf16 (4 VGPRs) MFMA frag
typedef __attribute__((ext_vector_type(4))) short short4v;
typedef __attribute__((ext_vector_type(2))) short short2v;
typedef __attribute__((ext_vector_type(4))) float f32x4;

#define MFMA(a, b, c) __builtin_amdgcn_mfma_f32_16x16x32_bf16(a, b, c, 0, 0, 0)

static __device__ __forceinline__ ushort_t f2bf(float x) {  // RNE, finite inputs only
  union { float f; unsigned u; } v; v.f = x;
  unsigned r = v.u + 0x7FFFu + ((v.u >> 16) & 1u);
  return (ushort_t)(r >> 16);
}
static __device__ __forceinline__ float bf2f(ushort_t h) {
  union { unsigned u; float f; } v; v.u = ((unsigned)h) << 16;
  return v.f;
}

// -------------------------------------------------------------------------
// Kernel 0: split q (fp32) -> qh/ql bf16 arrays, [b][512][128], pad rows = 0.
// -------------------------------------------------------------------------
__global__ __launch_bounds__(256) void conv_kernel(
    const float* __restrict__ q, ushort_t* __restrict__ qh,
    ushort_t* __restrict__ ql)
{
  int idx = blockIdx.x * 256 + threadIdx.x;   // 0 .. 131071 (16*512*16)
  int b  = idx >> 13;
  int r  = (idx >> 4) & 511;
  int c8 = (idx & 15) * 8;
  short8v h8 = {0,0,0,0,0,0,0,0}, l8 = {0,0,0,0,0,0,0,0};
  if (r < NG) {
    const float* src = &q[(size_t)(b * NG + r) * DIM + c8];
    float4 a = *(const float4*)src, d = *(const float4*)(src + 4);
    float vals[8] = {a.x, a.y, a.z, a.w, d.x, d.y, d.z, d.w};
#pragma unroll
    for (int j = 0; j < 8; ++j) {
      ushort_t hi = f2bf(vals[j]);
      h8[j] = (short)hi;
      l8[j] = (short)f2bf(vals[j] - bf2f(hi));
    }
  }
  size_t off = (size_t)(b * 512 + r) * DIM + c8;
  *(short8v*)&qh[off] = h8;
  *(short8v*)&ql[off] = l8;
}

// -------------------------------------------------------------------------
// Kernel 1: MFMA projections, split-precision (ql*wh + qh*wl + qh*wh).
//  Grid (2, NB, NH); 4 waves own col-tiles: w0{Wq,Wk} w1{Wv(swapped),W1}
//  w2{W2,W3} w3{W4}. W frags in regs (once per block); q frags from global.
//  Stores: Qc/K all rows; W1/W2 rows<=250 (row0=zero); W3/W4 rows>=251;
//  V swapped -> Vt[v][g] contiguous-g stores.
// -------------------------------------------------------------------------
__global__ __launch_bounds__(256) void proj_kernel(
    const ushort_t* __restrict__ qh_g, const ushort_t* __restrict__ ql_g,
    const float* __restrict__ wq, const float* __restrict__ wk,
    const float* __restrict__ wv, const float* __restrict__ w1,
    const float* __restrict__ w2, const float* __restrict__ w3,
    const float* __restrict__ w4,
    ushort_t* __restrict__ QcH, ushort_t* __restrict__ QcL,
    ushort_t* __restrict__ QPH, ushort_t* __restrict__ QPL,
    ushort_t* __restrict__ QDH, ushort_t* __restrict__ QDL,
    ushort_t* __restrict__ Kb,  ushort_t* __restrict__ Vt)
{
  const int half = blockIdx.x, b = blockIdx.y, h = blockIdx.z;
  const int tid = threadIdx.x;
  const int wid = tid >> 6, lane = tid & 63;
  const int lrow = lane & 15, kgrp = lane >> 4;
  const size_t hb = (size_t)h * NB + b;

  const float* Wptr[7] = {wq, wk, wv, w1, w2, w3, w4};
  const int p0 = wid * 2;
  const int p1 = (wid < 3) ? wid * 2 + 1 : -1;

  // W fragments: lane holds W[d = c*32+kgrp*8+j][col=lrow], hi/lo split
  short8v whf[2][4], wlf[2][4];
#pragma unroll
  for (int slot = 0; slot < 2; ++slot) {
    int p = slot ? p1 : p0;
    if (p < 0) continue;
    const float* W = Wptr[p] + h * 2048 + lrow;
#pragma unroll
    for (int c = 0; c < 4; ++c) {
      short8v hh, ll;
#pragma unroll
      for (int j = 0; j < 8; ++j) {
        float v = W[(c * 32 + kgrp * 8 + j) * 16];
        ushort_t hi = f2bf(v);
        hh[j] = (short)hi;
        ll[j] = (short)f2bf(v - bf2f(hi));
      }
      whf[slot][c] = hh; wlf[slot][c] = ll;
    }
  }

  const f32x4 zero4 = {0.f, 0.f, 0.f, 0.f};

#pragma unroll 1
  for (int iter = 0; iter < 8; ++iter) {
    const int rowbase = half * 256 + iter * 32;
    short8v qhf[2][4], qlf[2][4];
#pragma unroll
    for (int s = 0; s < 2; ++s)
#pragma unroll
      for (int c = 0; c < 4; ++c) {
        size_t off = (size_t)(b * 512 + rowbase + s * 16 + lrow) * DIM + c * 32 + kgrp * 8;
        qhf[s][c] = *(const short8v*)(qh_g + off);
        qlf[s][c] = *(const short8v*)(ql_g + off);
      }

    f32x4 acc[2][2] = {{zero4, zero4}, {zero4, zero4}};
#pragma unroll
    for (int c = 0; c < 4; ++c)
#pragma unroll
      for (int slot = 0; slot < 2; ++slot) {
        int p = slot ? p1 : p0;
        if (p < 0) continue;
#pragma unroll
        for (int s = 0; s < 2; ++s) {
          if (p == 2) {   // V: swapped operands -> C[v][g]
            acc[slot][s] = MFMA(whf[slot][c], qlf[s][c], acc[slot][s]);
            acc[slot][s] = MFMA(wlf[slot][c], qhf[s][c], acc[slot][s]);
            acc[slot][s] = MFMA(whf[slot][c], qhf[s][c], acc[slot][s]);
          } else {
            acc[slot][s] = MFMA(qlf[s][c], whf[slot][c], acc[slot][s]);
            acc[slot][s] = MFMA(qhf[s][c], wlf[slot][c], acc[slot][s]);
            acc[slot][s] = MFMA(qhf[s][c], whf[slot][c], acc[slot][s]);
          }
        }
      }

    // stores
#pragma unroll
    for (int slot = 0; slot < 2; ++slot) {
      int p = slot ? p1 : p0;
      if (p < 0) continue;
#pragma unroll
      for (int s = 0; s < 2; ++s) {
#pragma unroll
        for (int rg = 0; rg < 4; ++rg) {
          float x = acc[slot][s][rg];
          if (p == 2) {         // Vt[hb][v][g], bf16 hi only
            int v = kgrp * 4 + rg;
            int g = rowbase + s * 16 + lrow;
            Vt[hb * 8192 + (size_t)v * 512 + g] = f2bf(x);
          } else {
            int row = rowbase + s * 16 + kgrp * 4 + rg;
            if (p == 0) {
              float xs = x * QSCALE;
              ushort_t hi = f2bf(xs), lo = f2bf(xs - bf2f(hi));
              size_t off = hb * 8192 + (size_t)row * 16 + lrow;
              QcH[off] = hi; QcL[off] = lo;
            } else if (p == 1) {
              ushort_t hi = f2bf(x), lo = f2bf(x - bf2f(hi));
              size_t off = hb * 16384 + (size_t)row * 32 + lrow;
              Kb[off] = hi; Kb[off + 16] = lo;
            } else {
              // p=3: W1->QP rows<=NPK (row0 zero); p=4: W2->QD rows<=NPK;
              // p=5: W3->QP rows>=251; p=6: W4->QD rows>=251 (incl pads)
              bool lowr = (p == 3 || p == 4);
              bool write = lowr ? (row <= NPK) : (row > NPK);
              if (write) {
                float xs = (row == 0) ? 0.f : x * QSCALE;
                ushort_t hi = f2bf(xs), lo = f2bf(xs - bf2f(hi));
                ushort_t* dH = (p == 3 || p == 5) ? QPH : QDH;
                ushort_t* dL = (p == 3 || p == 5) ? QPL : QDL;
                size_t off = hb * 8192 + (size_t)row * 16 + lrow;
                dH[off] = hi; dL[off] = lo;
              }
            }
          }
        }
      }
    }
  }
}

// -------------------------------------------------------------------------
// Kernel 2: fused MFMA attention (core unchanged from R3; epilogue now
// stores Hd as bf16 hi/lo for the MFMA out-projection).
// -------------------------------------------------------------------------
__global__ __launch_bounds__(256, 2) void attn_kernel(
    const ushort_t* __restrict__ QcH, const ushort_t* __restrict__ QcL,
    const ushort_t* __restrict__ QPH, const ushort_t* __restrict__ QPL,
    const ushort_t* __restrict__ QDH, const ushort_t* __restrict__ QDL,
    const ushort_t* __restrict__ Kb,  const ushort_t* __restrict__ Vt,
    ushort_t* __restrict__ HdH, ushort_t* __restrict__ HdL)
{
  __shared__ __align__(16) ushort_t Klds[16384];      // [ch32][lcol16][lh4][8]
  __shared__ __align__(16) ushort_t Vlds[8192];       // [grp16][lh4][v16][8]
  __shared__ __align__(16) ushort_t Plds[4][32][40];  // per-wave P

  const int rt = blockIdx.x, b = blockIdx.y, h = blockIdx.z;
  const int tid = threadIdx.x;
  const int wid = tid >> 6, lane = tid & 63;
  const int lhalf = lane >> 4, lcol = lane & 15;
  const size_t hb = (size_t)h * NB + b;

  const ushort_t* Kg = Kb + hb * (size_t)(QROWS * 32);
  for (int c = tid; c < 2048; c += 256)
    *(short8v*)&Klds[c * 8] = *(const short8v*)(Kg + (size_t)c * 8);

  const ushort_t* Vg = Vt + hb * (size_t)(16 * QROWS);
#pragma unroll
  for (int it = 0; it < 4; ++it) {
    int c = it * 256 + tid;
    int blk = (it * 16) + (c & 15);
    int v = (c >> 4) & 15;
    int grp = blk >> 2, lh = blk & 3;
    short8v val = *(const short8v*)(Vg + (size_t)v * QROWS + blk * 8);
    *(short8v*)&Vlds[((grp * 4 + lh) * 16 + v) * 8] = val;
  }
  __syncthreads();

  const int wrow = rt * 128 + wid * 32;
  short8v qch[2], qcl[2], qph[2], qpl[2], qdh[2], qdl[2];
#pragma unroll
  for (int f = 0; f < 2; ++f) {
    int row = wrow + f * 16 + lcol;
    size_t off = hb * (size_t)(QROWS * 16) + (size_t)row * 16;
    size_t offh = off + (lhalf & 1) * 8;
    qch[f] = *(const short8v*)(QcH + offh);
    qph[f] = *(const short8v*)(QPH + offh);
    qdh[f] = *(const short8v*)(QDH + offh);
    short8v zl = {0,0,0,0,0,0,0,0};
    qcl[f] = zl; qpl[f] = zl; qdl[f] = zl;
    if (lhalf < 2) {
      size_t offl = off + lhalf * 8;
      qcl[f] = *(const short8v*)(QcL + offl);
      qpl[f] = *(const short8v*)(QPL + offl);
      qdl[f] = *(const short8v*)(QDL + offl);
    }
  }

  const f32x4 zero4 = {0.f, 0.f, 0.f, 0.f};
  f32x4 Oacc[2] = {zero4, zero4};
  float lsum[2] = {0.f, 0.f};
  ushort_t* Pw = &Plds[wid][0][0];

#pragma unroll 1
  for (int grp = 0; grp < 16; ++grp) {
#pragma unroll
    for (int half = 0; half < 2; ++half) {
      const int ch = grp * 2 + half;
      const int kbase = ch * 16;
      short8v ka = *(const short8v*)&Klds[((ch * 16 + lcol) * 4 + lhalf) * 8];
#pragma unroll
      for (int qf = 0; qf < 2; ++qf) {
        f32x4 sc = MFMA(ka, qcl[qf], zero4);
        sc = MFMA(ka, qch[qf], sc);
        f32x4 se;
        if (ch == 15) {
          f32x4 sp = MFMA(ka, qpl[qf], zero4); sp = MFMA(ka, qph[qf], sp);
          f32x4 sd = MFMA(ka, qdl[qf], zero4); sd = MFMA(ka, qdh[qf], sd);
#pragma unroll
          for (int rg = 0; rg < 4; ++rg) {
            int key = kbase + lhalf * 4 + rg;
            se[rg] = (key <= NPK) ? sp[rg] : sd[rg];
          }
        } else if (ch <= 14) {
          se = MFMA(ka, qpl[qf], zero4); se = MFMA(ka, qph[qf], se);
        } else {
          se = MFMA(ka, qdl[qf], zero4); se = MFMA(ka, qdh[qf], se);
        }
        float pv[4];
#pragma unroll
        for (int rg = 0; rg < 4; ++rg) {
          int key = kbase + lhalf * 4 + rg;
          float ec = __builtin_amdgcn_exp2f(sc[rg]);
          float ee = (se[rg] == 0.0f) ? 0.0f : __builtin_amdgcn_exp2f(se[rg]);
          float pt = ec + ((key >= 1) ? ee : 0.0f);
          pt = (key < NG) ? pt : 0.0f;
          pv[rg] = pt;
        }
        short4v pk;
        pk[0] = (short)f2bf(pv[0]); pk[1] = (short)f2bf(pv[1]);
        pk[2] = (short)f2bf(pv[2]); pk[3] = (short)f2bf(pv[3]);
        lsum[qf] += bf2f((ushort_t)pk[0]) + bf2f((ushort_t)pk[1]) +
                    bf2f((ushort_t)pk[2]) + bf2f((ushort_t)pk[3]);
        *(short4v*)&Pw[(qf * 16 + lcol) * 40 + half * 16 + lhalf * 4] = pk;
      }
    }
    asm volatile("s_waitcnt lgkmcnt(0)" ::: "memory");
    __builtin_amdgcn_sched_barrier(0);
#pragma unroll
    for (int qf = 0; qf < 2; ++qf) {
      short8v pa = *(const short8v*)&Pw[(qf * 16 + lcol) * 40 + lhalf * 8];
      short8v vb = *(const short8v*)&Vlds[((grp * 4 + lhalf) * 16 + lcol) * 8];
      Oacc[qf] = MFMA(pa, vb, Oacc[qf]);
    }
  }

#pragma unroll
  for (int qf = 0; qf < 2; ++qf) {
    float l = lsum[qf];
    l += __shfl_xor(l, 16);
    l += __shfl_xor(l, 32);
    float inv = 1.0f / l;
#pragma unroll
    for (int rg = 0; rg < 4; ++rg) {
      float invr = __shfl(inv, lhalf * 4 + rg);
      float o = Oacc[qf][rg] * invr;
      int row = wrow + qf * 16 + lhalf * 4 + rg;
      if (row < NG) {
        ushort_t hi = f2bf(o), lo = f2bf(o - bf2f(hi));
        size_t off = (hb * 512 + (size_t)row) * 16 + lcol;
        HdH[off] = hi; HdL[off] = lo;
      }
    }
  }
}

// -------------------------------------------------------------------------
// Kernel 3: MFMA output projection, split precision.
//  out[b,g,e] = sum_{hkd} Hd[h,b,g,kd] * Wout[hkd,e].  Block: 32 rows x 128 e.
// -------------------------------------------------------------------------
__global__ __launch_bounds__(256) void out_kernel(
    const ushort_t* __restrict__ HdH, const ushort_t* __restrict__ HdL,
    const float* __restrict__ Wout, float* __restrict__ out)
{
  const int b = blockIdx.x >> 4, rt = blockIdx.x & 15;
  const int tid = threadIdx.x;
  const int wid = tid >> 6, lane = tid & 63;
  const int lrow = lane & 15, kgrp = lane >> 4;

  // B frags: Wout[hkd][e], e-tiles wid*2, wid*2+1
  short8v bh[2][4], bl[2][4];
#pragma unroll
  for (int slot = 0; slot < 2; ++slot) {
    int e = (wid * 2 + slot) * 16 + lrow;
#pragma unroll
    for (int c = 0; c < 4; ++c) {
      short8v hh, ll;
#pragma unroll
      for (int j = 0; j < 8; ++j) {
        float v = Wout[(size_t)(c * 32 + kgrp * 8 + j) * 128 + e];
        ushort_t hi = f2bf(v);
        hh[j] = (short)hi;
        ll[j] = (short)f2bf(v - bf2f(hi));
      }
      bh[slot][c] = hh; bl[slot][c] = ll;
    }
  }

  // A frags: Hd rows (hi/lo), hkd = c*32+kgrp*8+j -> h=(c*4+kgrp)>>1, kd0=((c*4+kgrp)&1)*8
  short8v ah[2][4], al[2][4];
#pragma unroll
  for (int s = 0; s < 2; ++s)
#pragma unroll
    for (int c = 0; c < 4; ++c) {
      int hh = (c * 4 + kgrp) >> 1, kd0 = ((c * 4 + kgrp) & 1) * 8;
      size_t off = ((size_t)(hh * NB + b) * 512 + rt * 32 + s * 16 + lrow) * 16 + kd0;
      ah[s][c] = *(const short8v*)(HdH + off);
      al[s][c] = *(const short8v*)(HdL + off);
    }

  const f32x4 zero4 = {0.f, 0.f, 0.f, 0.f};
  f32x4 acc[2][2] = {{zero4, zero4}, {zero4, zero4}};
#pragma unroll
  for (int c = 0; c < 4; ++c)
#pragma unroll
    for (int slot = 0; slot < 2; ++slot)
#pragma unroll
      for (int s = 0; s < 2; ++s) {
        acc[slot][s] = MFMA(al[s][c], bh[slot][c], acc[slot][s]);
        acc[slot][s] = MFMA(ah[s][c], bl[slot][c], acc[slot][s]);
        acc[slot][s] = MFMA(ah[s][c], bh[slot][c], acc[slot][s]);
      }

#pragma unroll
  for (int slot = 0; slot < 2; ++slot)
#pragma unroll
    for (int s = 0; s < 2; ++s)
#pragma unroll
      for (int rg = 0; rg < 4; ++rg) {
        int g = rt * 32 + s * 16 + kgrp * 4 + rg;
        int e = (wid * 2 + slot) * 16 + lrow;
        if (g < NG) out[((size_t)b * NG + g) * 128 + e] = acc[slot][s][rg];
      }
}

// -------------------------------------------------------------------------
extern "C" void kernel_launch(void* const* d_in, const int* in_sizes, int n_in,
                              void* d_out, int out_size, void* d_ws, size_t ws_size,
                              hipStream_t stream)
{
  const float* q  = (const float*)d_in[0];
  const float* Wq = (const float*)d_in[1];
  const float* Wk = (const float*)d_in[2];
  const float* Wv = (const float*)d_in[3];
  const float* W1 = (const float*)d_in[4];
  const float* W2 = (const float*)d_in[5];
  const float* W3 = (const float*)d_in[6];
  const float* W4 = (const float*)d_in[7];
  const float* Wo = (const float*)d_in[8];
  float* out = (float*)d_out;

  char* wsb = (char*)d_ws;
  ushort_t* qh_g = (ushort_t*)(wsb + (0u  << 20));   // 2 MB [16][512][128]
  ushort_t* ql_g = (ushort_t*)(wsb + (2u  << 20));   // 2 MB
  ushort_t* QcH  = (ushort_t*)(wsb + (4u  << 20));   // 2 MB [128][512][16]
  ushort_t* QcL  = (ushort_t*)(wsb + (6u  << 20));
  ushort_t* QPH  = (ushort_t*)(wsb + (8u  << 20));
  ushort_t* QPL  = (ushort_t*)(wsb + (10u << 20));
  ushort_t* QDH  = (ushort_t*)(wsb + (12u << 20));
  ushort_t* QDL  = (ushort_t*)(wsb + (14u << 20));
  ushort_t* Kb   = (ushort_t*)(wsb + (16u << 20));   // 4 MB [128][512][32]
  ushort_t* Vt   = (ushort_t*)(wsb + (20u << 20));   // 2 MB [128][16][512]
  // Hd aliases the q split arrays (dead after proj_kernel; stream-ordered)
  ushort_t* HdH  = qh_g;                             // 2 MB [128][512][16]
  ushort_t* HdL  = ql_g;

  conv_kernel<<<dim3(512), 256, 0, stream>>>(q, qh_g, ql_g);
  proj_kernel<<<dim3(2, NB, NH), 256, 0, stream>>>(qh_g, ql_g,
                                                   Wq, Wk, Wv, W1, W2, W3, W4,
                                                   QcH, QcL, QPH, QPL, QDH, QDL, Kb, Vt);
  attn_kernel<<<dim3(4, NB, NH), 256, 0, stream>>>(QcH, QcL, QPH, QPL, QDH, QDL,
                                                   Kb, Vt, HdH, HdL);
  out_kernel<<<dim3(256), 256, 0, stream>>>(HdH, HdL, Wo, out);
}

// Round 5
// 129.901 us; speedup vs baseline: 2.3104x; 1.0276x over previous
//
#include <hip/hip_runtime.h>
#include <math.h>

// Problem constants (match reference setup_inputs)
#define NH 8
#define DIM 128
#define KD 16
#define NB 16
#define NG 501
#define NPK 250
#define QROWS 512                 // padded row count for projection arrays
// nf * log2(e) = 0.25 * 1.4426950408889634
#define QSCALE 0.36067376022224085f

typedef unsigned short ushort_t;
typedef __attribute__((ext_vector_type(8))) short short8v;   // 8 bf16 (4 VGPRs) MFMA frag
typedef __attribute__((ext_vector_type(4))) short short4v;
typedef __attribute__((ext_vector_type(2))) short short2v;
typedef __attribute__((ext_vector_type(4))) float f32x4;

#define MFMA(a, b, c) __builtin_amdgcn_mfma_f32_16x16x32_bf16(a, b, c, 0, 0, 0)

static __device__ __forceinline__ ushort_t f2bf(float x) {  // RNE, finite inputs only
  union { float f; unsigned u; } v; v.f = x;
  unsigned r = v.u + 0x7FFFu + ((v.u >> 16) & 1u);
  return (ushort_t)(r >> 16);
}
static __device__ __forceinline__ float bf2f(ushort_t h) {
  union { unsigned u; float f; } v; v.u = ((unsigned)h) << 16;
  return v.f;
}
static __device__ __forceinline__ unsigned cvtpk(float lo, float hi) {
  unsigned r;
  asm("v_cvt_pk_bf16_f32 %0, %1, %2" : "=v"(r) : "v"(lo), "v"(hi));
  return r;   // low16 = bf16(lo), high16 = bf16(hi), RNE
}

// -------------------------------------------------------------------------
// Kernel 0: split q (fp32) -> qh/ql bf16 arrays, [b][512][128], pad rows = 0.
// -------------------------------------------------------------------------
__global__ __launch_bounds__(256) void conv_kernel(
    const float* __restrict__ q, ushort_t* __restrict__ qh,
    ushort_t* __restrict__ ql)
{
  int idx = blockIdx.x * 256 + threadIdx.x;   // 0 .. 131071 (16*512*16)
  int b  = idx >> 13;
  int r  = (idx >> 4) & 511;
  int c8 = (idx & 15) * 8;
  short8v h8 = {0,0,0,0,0,0,0,0}, l8 = {0,0,0,0,0,0,0,0};
  if (r < NG) {
    const float* src = &q[(size_t)(b * NG + r) * DIM + c8];
    float4 a = *(const float4*)src, d = *(const float4*)(src + 4);
    float vals[8] = {a.x, a.y, a.z, a.w, d.x, d.y, d.z, d.w};
#pragma unroll
    for (int j = 0; j < 8; ++j) {
      ushort_t hi = f2bf(vals[j]);
      h8[j] = (short)hi;
      l8[j] = (short)f2bf(vals[j] - bf2f(hi));
    }
  }
  size_t off = (size_t)(b * 512 + r) * DIM + c8;
  *(short8v*)&qh[off] = h8;
  *(short8v*)&ql[off] = l8;
}

// -------------------------------------------------------------------------
// Kernel 1: MFMA projections, split-precision (ql*wh + qh*wl + qh*wh).
//  Grid (8, NB, NH) = 1024 blocks (4/CU); each block: 64 rows, 2 iters.
// -------------------------------------------------------------------------
__global__ __launch_bounds__(256) void proj_kernel(
    const ushort_t* __restrict__ qh_g, const ushort_t* __restrict__ ql_g,
    const float* __restrict__ wq, const float* __restrict__ wk,
    const float* __restrict__ wv, const float* __restrict__ w1,
    const float* __restrict__ w2, const float* __restrict__ w3,
    const float* __restrict__ w4,
    ushort_t* __restrict__ QcH, ushort_t* __restrict__ QcL,
    ushort_t* __restrict__ QPH, ushort_t* __restrict__ QPL,
    ushort_t* __restrict__ QDH, ushort_t* __restrict__ QDL,
    ushort_t* __restrict__ Kb,  ushort_t* __restrict__ Vt)
{
  const int rc = blockIdx.x, b = blockIdx.y, h = blockIdx.z;
  const int tid = threadIdx.x;
  const int wid = tid >> 6, lane = tid & 63;
  const int lrow = lane & 15, kgrp = lane >> 4;
  const size_t hb = (size_t)h * NB + b;

  const float* Wptr[7] = {wq, wk, wv, w1, w2, w3, w4};
  const int p0 = wid * 2;
  const int p1 = (wid < 3) ? wid * 2 + 1 : -1;

  // W fragments: lane holds W[d = c*32+kgrp*8+j][col=lrow], hi/lo split
  short8v whf[2][4], wlf[2][4];
#pragma unroll
  for (int slot = 0; slot < 2; ++slot) {
    int p = slot ? p1 : p0;
    if (p < 0) continue;
    const float* W = Wptr[p] + h * 2048 + lrow;
#pragma unroll
    for (int c = 0; c < 4; ++c) {
      short8v hh, ll;
#pragma unroll
      for (int j = 0; j < 8; ++j) {
        float v = W[(c * 32 + kgrp * 8 + j) * 16];
        ushort_t hi = f2bf(v);
        hh[j] = (short)hi;
        ll[j] = (short)f2bf(v - bf2f(hi));
      }
      whf[slot][c] = hh; wlf[slot][c] = ll;
    }
  }

  const f32x4 zero4 = {0.f, 0.f, 0.f, 0.f};

#pragma unroll 1
  for (int iter = 0; iter < 2; ++iter) {
    const int rowbase = rc * 64 + iter * 32;
    short8v qhf[2][4], qlf[2][4];
#pragma unroll
    for (int s = 0; s < 2; ++s)
#pragma unroll
      for (int c = 0; c < 4; ++c) {
        size_t off = (size_t)(b * 512 + rowbase + s * 16 + lrow) * DIM + c * 32 + kgrp * 8;
        qhf[s][c] = *(const short8v*)(qh_g + off);
        qlf[s][c] = *(const short8v*)(ql_g + off);
      }

    f32x4 acc[2][2] = {{zero4, zero4}, {zero4, zero4}};
#pragma unroll
    for (int c = 0; c < 4; ++c)
#pragma unroll
      for (int slot = 0; slot < 2; ++slot) {
        int p = slot ? p1 : p0;
        if (p < 0) continue;
#pragma unroll
        for (int s = 0; s < 2; ++s) {
          if (p == 2) {   // V: swapped operands -> C[v][g]
            acc[slot][s] = MFMA(whf[slot][c], qlf[s][c], acc[slot][s]);
            acc[slot][s] = MFMA(wlf[slot][c], qhf[s][c], acc[slot][s]);
            acc[slot][s] = MFMA(whf[slot][c], qhf[s][c], acc[slot][s]);
          } else {
            acc[slot][s] = MFMA(qlf[s][c], whf[slot][c], acc[slot][s]);
            acc[slot][s] = MFMA(qhf[s][c], wlf[slot][c], acc[slot][s]);
            acc[slot][s] = MFMA(qhf[s][c], whf[slot][c], acc[slot][s]);
          }
        }
      }

    // stores
#pragma unroll
    for (int slot = 0; slot < 2; ++slot) {
      int p = slot ? p1 : p0;
      if (p < 0) continue;
#pragma unroll
      for (int s = 0; s < 2; ++s) {
#pragma unroll
        for (int rg = 0; rg < 4; ++rg) {
          float x = acc[slot][s][rg];
          if (p == 2) {         // Vt[hb][v][g], bf16 hi only
            int v = kgrp * 4 + rg;
            int g = rowbase + s * 16 + lrow;
            Vt[hb * 8192 + (size_t)v * 512 + g] = f2bf(x);
          } else {
            int row = rowbase + s * 16 + kgrp * 4 + rg;
            if (p == 0) {
              float xs = x * QSCALE;
              ushort_t hi = f2bf(xs), lo = f2bf(xs - bf2f(hi));
              size_t off = hb * 8192 + (size_t)row * 16 + lrow;
              QcH[off] = hi; QcL[off] = lo;
            } else if (p == 1) {
              ushort_t hi = f2bf(x), lo = f2bf(x - bf2f(hi));
              size_t off = hb * 16384 + (size_t)row * 32 + lrow;
              Kb[off] = hi; Kb[off + 16] = lo;
            } else {
              bool lowr = (p == 3 || p == 4);
              bool write = lowr ? (row <= NPK) : (row > NPK);
              if (write) {
                float xs = (row == 0) ? 0.f : x * QSCALE;
                ushort_t hi = f2bf(xs), lo = f2bf(xs - bf2f(hi));
                ushort_t* dH = (p == 3 || p == 5) ? QPH : QDH;
                ushort_t* dL = (p == 3 || p == 5) ? QPL : QDL;
                size_t off = hb * 8192 + (size_t)row * 16 + lrow;
                dH[off] = hi; dL[off] = lo;
              }
            }
          }
        }
      }
    }
  }
}

// -------------------------------------------------------------------------
// Kernel 2: fused MFMA attention, in-register P-transpose (no P LDS tile,
// no per-group waitcnt). Swapped PV: O^T[v][q] = V^T x P^T; the V^T LDS
// read doubles as the A-frag; P^T B-frag built with cvt_pk + 8 shfl.
// -------------------------------------------------------------------------
__global__ __launch_bounds__(256, 2) void attn_kernel(
    const ushort_t* __restrict__ QcH, const ushort_t* __restrict__ QcL,
    const ushort_t* __restrict__ QPH, const ushort_t* __restrict__ QPL,
    const ushort_t* __restrict__ QDH, const ushort_t* __restrict__ QDL,
    const ushort_t* __restrict__ Kb,  const ushort_t* __restrict__ Vt,
    ushort_t* __restrict__ HdH, ushort_t* __restrict__ HdL)
{
  __shared__ __align__(16) ushort_t Klds[16384];      // [ch32][lcol16][lh4][8]
  __shared__ __align__(16) ushort_t Vlds[8192];       // [grp16][lh4][v16][8]

  const int rt = blockIdx.x, b = blockIdx.y, h = blockIdx.z;
  const int tid = threadIdx.x;
  const int wid = tid >> 6, lane = tid & 63;
  const int lhalf = lane >> 4, lcol = lane & 15;
  const size_t hb = (size_t)h * NB + b;

  const ushort_t* Kg = Kb + hb * (size_t)(QROWS * 32);
  for (int c = tid; c < 2048; c += 256)
    *(short8v*)&Klds[c * 8] = *(const short8v*)(Kg + (size_t)c * 8);

  const ushort_t* Vg = Vt + hb * (size_t)(16 * QROWS);
#pragma unroll
  for (int it = 0; it < 4; ++it) {
    int c = it * 256 + tid;
    int blk = (it * 16) + (c & 15);
    int v = (c >> 4) & 15;
    int grp = blk >> 2, lh = blk & 3;
    short8v val = *(const short8v*)(Vg + (size_t)v * QROWS + blk * 8);
    *(short8v*)&Vlds[((grp * 4 + lh) * 16 + v) * 8] = val;
  }
  __syncthreads();

  // Q fragments: hi all lanes ([Qh|Qh] vs K=[Kh|Kl]); lo zero in lanes >=32
  const int wrow = rt * 128 + wid * 32;
  short8v qch[2], qcl[2], qph[2], qpl[2], qdh[2], qdl[2];
#pragma unroll
  for (int f = 0; f < 2; ++f) {
    int row = wrow + f * 16 + lcol;
    size_t off = hb * (size_t)(QROWS * 16) + (size_t)row * 16;
    size_t offh = off + (lhalf & 1) * 8;
    qch[f] = *(const short8v*)(QcH + offh);
    qph[f] = *(const short8v*)(QPH + offh);
    qdh[f] = *(const short8v*)(QDH + offh);
    short8v zl = {0,0,0,0,0,0,0,0};
    qcl[f] = zl; qpl[f] = zl; qdl[f] = zl;
    if (lhalf < 2) {
      size_t offl = off + lhalf * 8;
      qcl[f] = *(const short8v*)(QcL + offl);
      qpl[f] = *(const short8v*)(QPL + offl);
      qdl[f] = *(const short8v*)(QDL + offl);
    }
  }

  const f32x4 zero4 = {0.f, 0.f, 0.f, 0.f};
  f32x4 Oacc[2] = {zero4, zero4};
  float lsum[2] = {0.f, 0.f};
  const int srcA = ((lhalf & 1) * 2) * 16 + lcol;   // B-frag source lanes
  const int srcB = srcA + 16;
  const bool selhi = (lhalf >= 2);

#pragma unroll 1
  for (int grp = 0; grp < 16; ++grp) {
    float pv[2][2][4];   // [half][qf][rg]
#pragma unroll
    for (int half = 0; half < 2; ++half) {
      const int ch = grp * 2 + half;
      short8v ka = *(const short8v*)&Klds[((ch * 16 + lcol) * 4 + lhalf) * 8];
#pragma unroll
      for (int qf = 0; qf < 2; ++qf) {
        f32x4 sc = MFMA(ka, qcl[qf], zero4);
        sc = MFMA(ka, qch[qf], sc);
        f32x4 se;
        if (ch == 15) {                        // straddles pick/del at 250/251
          f32x4 sp = MFMA(ka, qpl[qf], zero4); sp = MFMA(ka, qph[qf], sp);
          f32x4 sd = MFMA(ka, qdl[qf], zero4); sd = MFMA(ka, qdh[qf], sd);
#pragma unroll
          for (int rg = 0; rg < 4; ++rg) {
            int key = 240 + lhalf * 4 + rg;
            se[rg] = (key <= NPK) ? sp[rg] : sd[rg];
          }
        } else if (ch <= 14) {                 // pure pick-key range
          se = MFMA(ka, qpl[qf], zero4); se = MFMA(ka, qph[qf], se);
        } else {                               // pure delivery-key range
          se = MFMA(ka, qdl[qf], zero4); se = MFMA(ka, qdh[qf], se);
        }
#pragma unroll
        for (int rg = 0; rg < 4; ++rg) {
          float ec = __builtin_amdgcn_exp2f(sc[rg]);
          float ee = (se[rg] == 0.0f) ? 0.0f : __builtin_amdgcn_exp2f(se[rg]); // zmask
          if (ch == 0 && rg == 0) ee = (lhalf == 0) ? 0.0f : ee;  // key 0: comp only
          float pt = ec + ee;
          if (ch == 31) pt = (lhalf * 4 + rg <= 4) ? pt : 0.0f;   // keys > 500
          lsum[qf] += pt;
          pv[half][qf][rg] = pt;
        }
      }
    }
    // In-register transpose to P^T B-frag: lane (lh,q) needs grp-keys lh*8..+7
#pragma unroll
    for (int qf = 0; qf < 2; ++qf) {
      unsigned a0 = cvtpk(pv[0][qf][0], pv[0][qf][1]);
      unsigned a1 = cvtpk(pv[0][qf][2], pv[0][qf][3]);
      unsigned b0 = cvtpk(pv[1][qf][0], pv[1][qf][1]);
      unsigned b1 = cvtpk(pv[1][qf][2], pv[1][qf][3]);
      unsigned h0A = (unsigned)__shfl((int)a0, srcA);
      unsigned h0B = (unsigned)__shfl((int)a1, srcA);
      unsigned h0C = (unsigned)__shfl((int)a0, srcB);
      unsigned h0D = (unsigned)__shfl((int)a1, srcB);
      unsigned h1A = (unsigned)__shfl((int)b0, srcA);
      unsigned h1B = (unsigned)__shfl((int)b1, srcA);
      unsigned h1C = (unsigned)__shfl((int)b0, srcB);
      unsigned h1D = (unsigned)__shfl((int)b1, srcB);
      union { unsigned u[4]; short8v s; } pb;
      pb.u[0] = selhi ? h1A : h0A;
      pb.u[1] = selhi ? h1B : h0B;
      pb.u[2] = selhi ? h1C : h0C;
      pb.u[3] = selhi ? h1D : h0D;
      short8v va = *(const short8v*)&Vlds[((grp * 4 + lhalf) * 16 + lcol) * 8];
      Oacc[qf] = MFMA(va, pb.s, Oacc[qf]);   // O^T[v=lh*4+rg][q=lcol]
    }
  }

  // epilogue: inv is same-lane (q = lcol); store 4 consecutive v as 8B
#pragma unroll
  for (int qf = 0; qf < 2; ++qf) {
    float l = lsum[qf];
    l += __shfl_xor(l, 16);
    l += __shfl_xor(l, 32);
    float inv = 1.0f / l;
    int row = wrow + qf * 16 + lcol;
    if (row < NG) {
      short4v ph, pl;
#pragma unroll
      for (int rg = 0; rg < 4; ++rg) {
        float o = Oacc[qf][rg] * inv;
        ushort_t hi = f2bf(o);
        ph[rg] = (short)hi;
        pl[rg] = (short)f2bf(o - bf2f(hi));
      }
      size_t off = (hb * 512 + (size_t)row) * 16 + lhalf * 4;
      *(short4v*)&HdH[off] = ph;
      *(short4v*)&HdL[off] = pl;
    }
  }
}

// -------------------------------------------------------------------------
// Kernel 3: MFMA output projection, split precision.
//  Grid (2, 16, NB) = 512 blocks; block: 32 rows x 64 e (wave = 16 e).
// -------------------------------------------------------------------------
__global__ __launch_bounds__(256) void out_kernel(
    const ushort_t* __restrict__ HdH, const ushort_t* __restrict__ HdL,
    const float* __restrict__ Wout, float* __restrict__ out)
{
  const int eh = blockIdx.x, rt = blockIdx.y, b = blockIdx.z;
  const int tid = threadIdx.x;
  const int wid = tid >> 6, lane = tid & 63;
  const int lrow = lane & 15, kgrp = lane >> 4;
  const int e0 = eh * 64 + wid * 16 + lrow;

  // B frags: Wout[hkd][e]
  short8v bh[4], bl[4];
#pragma unroll
  for (int c = 0; c < 4; ++c) {
    short8v hh, ll;
#pragma unroll
    for (int j = 0; j < 8; ++j) {
      float v = Wout[(size_t)(c * 32 + kgrp * 8 + j) * 128 + e0];
      ushort_t hi = f2bf(v);
      hh[j] = (short)hi;
      ll[j] = (short)f2bf(v - bf2f(hi));
    }
    bh[c] = hh; bl[c] = ll;
  }

  // A frags: Hd rows (hi/lo); hkd = c*32+kgrp*8+j
  short8v ah[2][4], al[2][4];
#pragma unroll
  for (int s = 0; s < 2; ++s)
#pragma unroll
    for (int c = 0; c < 4; ++c) {
      int hh = (c * 4 + kgrp) >> 1, kd0 = ((c * 4 + kgrp) & 1) * 8;
      size_t off = ((size_t)(hh * NB + b) * 512 + rt * 32 + s * 16 + lrow) * 16 + kd0;
      ah[s][c] = *(const short8v*)(HdH + off);
      al[s][c] = *(const short8v*)(HdL + off);
    }

  const f32x4 zero4 = {0.f, 0.f, 0.f, 0.f};
  f32x4 acc[2] = {zero4, zero4};
#pragma unroll
  for (int c = 0; c < 4; ++c)
#pragma unroll
    for (int s = 0; s < 2; ++s) {
      acc[s] = MFMA(al[s][c], bh[c], acc[s]);
      acc[s] = MFMA(ah[s][c], bl[c], acc[s]);
      acc[s] = MFMA(ah[s][c], bh[c], acc[s]);
    }

#pragma unroll
  for (int s = 0; s < 2; ++s)
#pragma unroll
    for (int rg = 0; rg < 4; ++rg) {
      int g = rt * 32 + s * 16 + kgrp * 4 + rg;
      if (g < NG) out[((size_t)b * NG + g) * 128 + e0] = acc[s][rg];
    }
}

// -------------------------------------------------------------------------
extern "C" void kernel_launch(void* const* d_in, const int* in_sizes, int n_in,
                              void* d_out, int out_size, void* d_ws, size_t ws_size,
                              hipStream_t stream)
{
  const float* q  = (const float*)d_in[0];
  const float* Wq = (const float*)d_in[1];
  const float* Wk = (const float*)d_in[2];
  const float* Wv = (const float*)d_in[3];
  const float* W1 = (const float*)d_in[4];
  const float* W2 = (const float*)d_in[5];
  const float* W3 = (const float*)d_in[6];
  const float* W4 = (const float*)d_in[7];
  const float* Wo = (const float*)d_in[8];
  float* out = (float*)d_out;

  char* wsb = (char*)d_ws;
  ushort_t* qh_g = (ushort_t*)(wsb + (0u  << 20));   // 2 MB [16][512][128]
  ushort_t* ql_g = (ushort_t*)(wsb + (2u  << 20));   // 2 MB
  ushort_t* QcH  = (ushort_t*)(wsb + (4u  << 20));   // 2 MB [128][512][16]
  ushort_t* QcL  = (ushort_t*)(wsb + (6u  << 20));
  ushort_t* QPH  = (ushort_t*)(wsb + (8u  << 20));
  ushort_t* QPL  = (ushort_t*)(wsb + (10u << 20));
  ushort_t* QDH  = (ushort_t*)(wsb + (12u << 20));
  ushort_t* QDL  = (ushort_t*)(wsb + (14u << 20));
  ushort_t* Kb   = (ushort_t*)(wsb + (16u << 20));   // 4 MB [128][512][32]
  ushort_t* Vt   = (ushort_t*)(wsb + (20u << 20));   // 2 MB [128][16][512]
  // Hd aliases the q split arrays (dead after proj_kernel; stream-ordered)
  ushort_t* HdH  = qh_g;                             // 2 MB [128][512][16]
  ushort_t* HdL  = ql_g;

  conv_kernel<<<dim3(512), 256, 0, stream>>>(q, qh_g, ql_g);
  proj_kernel<<<dim3(8, NB, NH), 256, 0, stream>>>(qh_g, ql_g,
                                                   Wq, Wk, Wv, W1, W2, W3, W4,
                                                   QcH, QcL, QPH, QPL, QDH, QDL, Kb, Vt);
  attn_kernel<<<dim3(4, NB, NH), 256, 0, stream>>>(QcH, QcL, QPH, QPL, QDH, QDL,
                                                   Kb, Vt, HdH, HdL);
  out_kernel<<<dim3(2, 16, NB), 256, 0, stream>>>(HdH, HdL, Wo, out);
}